// Round 1
// baseline (8274.214 us; speedup 1.0000x reference)
//
#include <hip/hip_runtime.h>
#include <math.h>

#define THREADS 256

__device__ __forceinline__ float gelu_exact(float v) {
    return 0.5f * v * (1.0f + erff(v * 0.70710678118654752f));
}

// ---------------- Kernel 1: PropertyNormalizer (xn) ----------------
__global__ void __launch_bounds__(THREADS) xn_kernel(const float* __restrict__ x,
                                                     float* __restrict__ out, int total) {
    int i = blockIdx.x * blockDim.x + threadIdx.x;
    if (i >= total) return;
    int col = i % 35;
    float v = x[i];
    float lo = 0.f, hi = 0.f;
    bool bin = true;
    switch (col) {
        case 23: lo = -4.5f;  hi = 4.5f;   break;
        case 24: lo = -2.0f;  hi = 2.0f;   break;
        case 25: lo = 75.0f;  hi = 204.0f; break;
        case 26: lo = 60.0f;  hi = 230.0f; break;
        case 32: lo = 0.0f;   hi = 1.0f;   break;
        case 34: lo = 0.0f;   hi = 100.0f; break;
        default: bin = false; break;
    }
    if (bin) {
        float vc = fminf(fmaxf(v, lo), hi);
        float vn = (vc - lo) / (hi - lo + 1e-6f);
        v = floorf(vn * 10.0f) / 10.0f;
    }
    out[i] = v;
}

// ---------------- Kernel 2: spatial encoder + scatter-sum ----------------
// one thread per edge; weights staged in LDS (uniform reads -> broadcast, conflict-free)
__global__ void __launch_bounds__(THREADS) spatial_kernel(
        const float* __restrict__ pos, const int* __restrict__ edge_index,
        const float* __restrict__ w1, const float* __restrict__ b1,
        const float* __restrict__ lng, const float* __restrict__ lnb,
        const float* __restrict__ w2, const float* __restrict__ b2,
        float* __restrict__ agg, float* __restrict__ deg, int E) {
    __shared__ float sW1[96], sB1[32], sG[32], sLB[32], sW2[1024], sB2[32];
    for (int i = threadIdx.x; i < 1024; i += blockDim.x) sW2[i] = w2[i];
    for (int i = threadIdx.x; i < 96; i += blockDim.x) sW1[i] = w1[i];
    if (threadIdx.x < 32) {
        sB1[threadIdx.x] = b1[threadIdx.x];
        sG[threadIdx.x]  = lng[threadIdx.x];
        sLB[threadIdx.x] = lnb[threadIdx.x];
        sB2[threadIdx.x] = b2[threadIdx.x];
    }
    __syncthreads();

    int e = blockIdx.x * blockDim.x + threadIdx.x;
    if (e >= E) return;
    int s = edge_index[e];
    int d = edge_index[E + e];

    float rx = pos[3 * d + 0] - pos[3 * s + 0];
    float ry = pos[3 * d + 1] - pos[3 * s + 1];
    float rz = pos[3 * d + 2] - pos[3 * s + 2];
    float dist = sqrtf(rx * rx + ry * ry + rz * rz);
    float inv = 1.0f / (dist + 1e-6f);
    rx *= inv; ry *= inv; rz *= inv;

    float g[32];
    float mean = 0.f;
    #pragma unroll
    for (int j = 0; j < 32; ++j) {
        float h = sB1[j] + rx * sW1[j] + ry * sW1[32 + j] + rz * sW1[64 + j];
        g[j] = h;
        mean += h;
    }
    mean *= (1.0f / 32.0f);
    float var = 0.f;
    #pragma unroll
    for (int j = 0; j < 32; ++j) { float t = g[j] - mean; var += t * t; }
    var *= (1.0f / 32.0f);
    float rstd = rsqrtf(var + 1e-5f);
    #pragma unroll
    for (int j = 0; j < 32; ++j) {
        float t = (g[j] - mean) * rstd * sG[j] + sLB[j];
        g[j] = gelu_exact(t);
    }

    float* aggd = agg + (size_t)d * 32;
    #pragma unroll 4
    for (int j = 0; j < 32; ++j) {
        float o = sB2[j];
        #pragma unroll
        for (int k = 0; k < 32; ++k) o += g[k] * sW2[k * 32 + j];
        atomicAdd(&aggd[j], o);
    }
    atomicAdd(&deg[d], 1.0f);
}

// ---------------- Kernel 3: pos_emb = agg / max(deg,1) ----------------
__global__ void __launch_bounds__(THREADS) posemb_kernel(const float* __restrict__ agg,
                                                         const float* __restrict__ deg,
                                                         float* __restrict__ out, int total) {
    int i = blockIdx.x * blockDim.x + threadIdx.x;
    if (i >= total) return;
    out[i] = agg[i] / fmaxf(deg[i >> 5], 1.0f);
}

// ---------------- Kernel 4: heterogeneous EdgeProcessor ----------------
// one wave (64 lanes) per edge, lane = output channel; coalesced 256B store/edge
__global__ void __launch_bounds__(THREADS) edgeproc_kernel(
        const float* __restrict__ edge_attr, const int* __restrict__ edge_type,
        const float* __restrict__ e_w, const float* __restrict__ e_b,
        const float* __restrict__ e_g, const float* __restrict__ e_lb,
        float* __restrict__ ef, int E) {
    __shared__ float sW[4096];           // [4][16][64]
    __shared__ float sB[256], sG[256], sLB[256];
    for (int i = threadIdx.x; i < 4096; i += blockDim.x) sW[i] = e_w[i];
    if (threadIdx.x < 256) {
        sB[threadIdx.x]  = e_b[threadIdx.x];
        sG[threadIdx.x]  = e_g[threadIdx.x];
        sLB[threadIdx.x] = e_lb[threadIdx.x];
    }
    __syncthreads();

    int e = (int)((blockIdx.x * (unsigned)blockDim.x + threadIdx.x) >> 6);
    int lane = threadIdx.x & 63;
    if (e >= E) return;

    int t = edge_type[e];
    const float4* xr = (const float4*)(edge_attr + (size_t)e * 16);
    float4 x0 = xr[0], x1 = xr[1], x2 = xr[2], x3 = xr[3];

    const float* W = sW + t * 1024;      // [16][64]
    float acc = sB[t * 64 + lane];
    acc += x0.x * W[0 * 64 + lane];  acc += x0.y * W[1 * 64 + lane];
    acc += x0.z * W[2 * 64 + lane];  acc += x0.w * W[3 * 64 + lane];
    acc += x1.x * W[4 * 64 + lane];  acc += x1.y * W[5 * 64 + lane];
    acc += x1.z * W[6 * 64 + lane];  acc += x1.w * W[7 * 64 + lane];
    acc += x2.x * W[8 * 64 + lane];  acc += x2.y * W[9 * 64 + lane];
    acc += x2.z * W[10 * 64 + lane]; acc += x2.w * W[11 * 64 + lane];
    acc += x3.x * W[12 * 64 + lane]; acc += x3.y * W[13 * 64 + lane];
    acc += x3.z * W[14 * 64 + lane]; acc += x3.w * W[15 * 64 + lane];

    // LayerNorm over the wave's 64 lanes (butterfly reduction)
    float s1 = acc, s2 = acc * acc;
    #pragma unroll
    for (int m = 1; m < 64; m <<= 1) {
        s1 += __shfl_xor(s1, m, 64);
        s2 += __shfl_xor(s2, m, 64);
    }
    float mean = s1 * (1.0f / 64.0f);
    float var  = s2 * (1.0f / 64.0f) - mean * mean;
    float rstd = rsqrtf(var + 1e-5f);
    float ny = (acc - mean) * rstd * sG[t * 64 + lane] + sLB[t * 64 + lane];
    ef[(size_t)e * 64 + lane] = gelu_exact(ny);
}

extern "C" void kernel_launch(void* const* d_in, const int* in_sizes, int n_in,
                              void* d_out, int out_size, void* d_ws, size_t ws_size,
                              hipStream_t stream) {
    const float* x         = (const float*)d_in[0];
    const float* pos       = (const float*)d_in[1];
    const float* edge_attr = (const float*)d_in[2];
    const float* sp_w1     = (const float*)d_in[3];
    const float* sp_b1     = (const float*)d_in[4];
    const float* sp_ln_g   = (const float*)d_in[5];
    const float* sp_ln_b   = (const float*)d_in[6];
    const float* sp_w2     = (const float*)d_in[7];
    const float* sp_b2     = (const float*)d_in[8];
    const float* e_w       = (const float*)d_in[9];
    const float* e_b       = (const float*)d_in[10];
    const float* e_ln_g    = (const float*)d_in[11];
    const float* e_ln_b    = (const float*)d_in[12];
    const int*   edge_index= (const int*)d_in[13];
    const int*   edge_type = (const int*)d_in[14];

    const int N = in_sizes[0] / 35;
    const int E = in_sizes[2] / 16;

    float* out     = (float*)d_out;
    float* xn      = out;
    float* pos_emb = out + (size_t)N * 35;
    float* ef      = pos_emb + (size_t)N * 32;

    float* agg = (float*)d_ws;            // [N][32]
    float* deg = agg + (size_t)N * 32;    // [N]

    hipMemsetAsync(agg, 0, (size_t)N * 33 * sizeof(float), stream);

    {   // xn
        int total = N * 35;
        xn_kernel<<<(total + THREADS - 1) / THREADS, THREADS, 0, stream>>>(x, xn, total);
    }
    {   // spatial encoder + scatter
        spatial_kernel<<<(E + THREADS - 1) / THREADS, THREADS, 0, stream>>>(
            pos, edge_index, sp_w1, sp_b1, sp_ln_g, sp_ln_b, sp_w2, sp_b2, agg, deg, E);
    }
    {   // pos_emb finalize
        int total = N * 32;
        posemb_kernel<<<(total + THREADS - 1) / THREADS, THREADS, 0, stream>>>(agg, deg, pos_emb, total);
    }
    {   // edge processor: one wave per edge
        long long waves = E;
        long long blocks = (waves * 64 + THREADS - 1) / THREADS;
        edgeproc_kernel<<<(int)blocks, THREADS, 0, stream>>>(
            edge_attr, edge_type, e_w, e_b, e_ln_g, e_ln_b, ef, E);
    }
}